// Round 2
// baseline (396.421 us; speedup 1.0000x reference)
//
#include <hip/hip_runtime.h>
#include <hip/hip_bf16.h>

// GCN anomaly detector: 2x GCNConv(128->128, relu) + linear(128->1).
// Pipeline: deg histogram -> scan -> CSR fill -> [GEMM*dinv -> gather-agg(+bias,relu)] x2
// with layer-2 agg fused with the final Wf dot product. All fp32.

#define FDIM 128

// ---------------- CSR build ----------------

__global__ void k_deg(const int* __restrict__ dst, int* __restrict__ deg, int E) {
    int e = blockIdx.x * 256 + threadIdx.x;
    if (e < E) atomicAdd(&deg[dst[e]], 1);
}

__global__ void k_scan1(const int* __restrict__ deg, int* __restrict__ row_ptr,
                        int* __restrict__ blockSum, int n) {
    __shared__ int wsum[16];
    int i = blockIdx.x * 1024 + threadIdx.x;
    int lane = threadIdx.x & 63, wid = threadIdx.x >> 6;
    int v = (i < n) ? deg[i] : 0;
    int x = v;
    #pragma unroll
    for (int off = 1; off < 64; off <<= 1) {
        int y = __shfl_up(x, off);
        if (lane >= off) x += y;
    }
    if (lane == 63) wsum[wid] = x;
    __syncthreads();
    if (wid == 0) {
        int s = (lane < 16) ? wsum[lane] : 0;
        #pragma unroll
        for (int off = 1; off < 16; off <<= 1) {
            int y = __shfl_up(s, off);
            if (lane >= off) s += y;
        }
        if (lane < 16) wsum[lane] = s;
    }
    __syncthreads();
    int add = wid ? wsum[wid - 1] : 0;
    int incl = x + add;
    if (i < n) row_ptr[i + 1] = incl;
    if (threadIdx.x == 1023) blockSum[blockIdx.x] = incl;
}

__global__ void k_scan2(const int* __restrict__ blockSum, int* __restrict__ blockOff, int nb) {
    int lane = threadIdx.x;  // 64 threads, nb <= 64 required (N <= 65536)
    int v = (lane < nb) ? blockSum[lane] : 0;
    int x = v;
    #pragma unroll
    for (int off = 1; off < 64; off <<= 1) {
        int y = __shfl_up(x, off);
        if (lane >= off) x += y;
    }
    blockOff[lane] = x - v;  // exclusive
}

__global__ void k_scan3(int* __restrict__ row_ptr, int* __restrict__ cursor,
                        const int* __restrict__ blockOff, const int* __restrict__ deg,
                        float* __restrict__ dinv, int n) {
    int i = blockIdx.x * 256 + threadIdx.x;
    if (i > n) return;
    if (i == 0) {
        row_ptr[0] = 0;
        cursor[0] = 0;
    } else {
        int b = (i - 1) >> 10;
        int val = row_ptr[i] + blockOff[b];
        row_ptr[i] = val;
        cursor[i] = val;
    }
    if (i < n) dinv[i] = rsqrtf((float)deg[i] + 1.0f);  // +1 self loop; always > 0
}

__global__ void k_fill(const int* __restrict__ src, const int* __restrict__ dst,
                       int* __restrict__ cursor, int* __restrict__ col, int E) {
    int e = blockIdx.x * 256 + threadIdx.x;
    if (e < E) {
        int pos = atomicAdd(&cursor[dst[e]], 1);
        col[pos] = src[e];
    }
}

// ---------------- GEMM: Y[r,:] = (X @ W)[r,:] * dinv[r] ----------------
// M x 128 @ 128 x 128. Block: 256 thr, 32 rows x 128 cols, K chunked by 64.
// LDS 40KB -> 4 blocks/CU.
// NOTE: macro params must not collide with .x/.y/.z/.w member tokens.

#define FMA4(av, xs, wv) { (av).x += (xs) * (wv).x; (av).y += (xs) * (wv).y; \
                           (av).z += (xs) * (wv).z; (av).w += (xs) * (wv).w; }

__global__ __launch_bounds__(256) void k_gemm(const float* __restrict__ X,
                                              const float* __restrict__ W,
                                              const float* __restrict__ dinv,
                                              float* __restrict__ Y, int M) {
    __shared__ float4 Xs[32][16];  // [row][k4]  8 KB
    __shared__ float4 Ws[64][32];  // [k][col4] 32 KB
    const int t = threadIdx.x;
    const int tx = t & 31;   // col4 group: cols 4*tx..4*tx+3
    const int ty = t >> 5;   // row group:  rows 4*ty..4*ty+3
    const int rb = blockIdx.x * 32;

    float4 acc[4];
    #pragma unroll
    for (int i = 0; i < 4; ++i) acc[i] = make_float4(0.f, 0.f, 0.f, 0.f);

    for (int kc = 0; kc < 2; ++kc) {
        // stage X tile: 32 rows x 64 k = 512 float4
        #pragma unroll
        for (int it = 0; it < 2; ++it) {
            int idx = t + it * 256;
            int r = idx >> 4, j = idx & 15;
            int gr = rb + r;
            float4 v = make_float4(0.f, 0.f, 0.f, 0.f);
            if (gr < M) v = *(const float4*)&X[(size_t)gr * FDIM + kc * 64 + 4 * j];
            Xs[r][j] = v;
        }
        // stage W chunk: 64 k x 128 cols = 2048 float4
        #pragma unroll
        for (int it = 0; it < 8; ++it) {
            int idx = t + it * 256;
            int kk = idx >> 5, c4 = idx & 31;
            Ws[kk][c4] = *(const float4*)&W[(size_t)(kc * 64 + kk) * FDIM + 4 * c4];
        }
        __syncthreads();
        #pragma unroll
        for (int k4 = 0; k4 < 16; ++k4) {
            float4 x0 = Xs[ty * 4 + 0][k4];
            float4 x1 = Xs[ty * 4 + 1][k4];
            float4 x2 = Xs[ty * 4 + 2][k4];
            float4 x3 = Xs[ty * 4 + 3][k4];
            float4 w0 = Ws[k4 * 4 + 0][tx];
            float4 w1 = Ws[k4 * 4 + 1][tx];
            float4 w2 = Ws[k4 * 4 + 2][tx];
            float4 w3 = Ws[k4 * 4 + 3][tx];
            FMA4(acc[0], x0.x, w0) FMA4(acc[0], x0.y, w1) FMA4(acc[0], x0.z, w2) FMA4(acc[0], x0.w, w3)
            FMA4(acc[1], x1.x, w0) FMA4(acc[1], x1.y, w1) FMA4(acc[1], x1.z, w2) FMA4(acc[1], x1.w, w3)
            FMA4(acc[2], x2.x, w0) FMA4(acc[2], x2.y, w1) FMA4(acc[2], x2.z, w2) FMA4(acc[2], x2.w, w3)
            FMA4(acc[3], x3.x, w0) FMA4(acc[3], x3.y, w1) FMA4(acc[3], x3.z, w2) FMA4(acc[3], x3.w, w3)
        }
        __syncthreads();
    }
    #pragma unroll
    for (int i = 0; i < 4; ++i) {
        int gr = rb + ty * 4 + i;
        if (gr < M) {
            float s = dinv[gr];
            float4 a = acc[i];
            a.x *= s; a.y *= s; a.z *= s; a.w *= s;
            *(float4*)&Y[(size_t)gr * FDIM + 4 * tx] = a;
        }
    }
}

// ---------------- Aggregation: h[d,:] = relu(dinv[d]*(y[d,:] + sum_{s in N(d)} y[s,:]) + b) ----
// One wave per node; lane holds 2 features (float2). FINAL fuses h . Wf + bf -> out[d].

template <bool FINAL>
__global__ __launch_bounds__(256) void k_agg(const float* __restrict__ y,
                                             const float* __restrict__ bvec,
                                             const float* __restrict__ dinv,
                                             const int* __restrict__ row_ptr,
                                             const int* __restrict__ col,
                                             float* __restrict__ h,
                                             const float* __restrict__ Wf,
                                             const float* __restrict__ bf,
                                             float* __restrict__ out, int n) {
    int wid = threadIdx.x >> 6, lane = threadIdx.x & 63;
    int node = blockIdx.x * 4 + wid;
    if (node >= n) return;
    int beg = row_ptr[node], end = row_ptr[node + 1];
    float2 acc = *(const float2*)&y[(size_t)node * FDIM + lane * 2];  // self loop (already *dinv[node])
    for (int e = beg; e < end; ++e) {
        int s = col[e];
        float2 v = *(const float2*)&y[(size_t)s * FDIM + lane * 2];
        acc.x += v.x;
        acc.y += v.y;
    }
    float dn = dinv[node];
    float2 bb = *(const float2*)&bvec[lane * 2];
    float ox = fmaxf(acc.x * dn + bb.x, 0.f);
    float oy = fmaxf(acc.y * dn + bb.y, 0.f);
    if (FINAL) {
        float2 wf = *(const float2*)&Wf[lane * 2];
        float s = ox * wf.x + oy * wf.y;
        #pragma unroll
        for (int off = 32; off > 0; off >>= 1) s += __shfl_xor(s, off);
        if (lane == 0) out[node] = s + bf[0];
    } else {
        *(float2*)&h[(size_t)node * FDIM + lane * 2] = make_float2(ox, oy);
    }
}

// ---------------- launch ----------------

extern "C" void kernel_launch(void* const* d_in, const int* in_sizes, int n_in,
                              void* d_out, int out_size, void* d_ws, size_t ws_size,
                              hipStream_t stream) {
    const float* x  = (const float*)d_in[0];
    const int*   ei = (const int*)d_in[1];
    const float* W1 = (const float*)d_in[2];
    const float* b1 = (const float*)d_in[3];
    const float* W2 = (const float*)d_in[4];
    const float* b2 = (const float*)d_in[5];
    const float* Wf = (const float*)d_in[6];
    const float* bf = (const float*)d_in[7];

    const int N = in_sizes[0] / FDIM;
    const int E = in_sizes[1] / 2;
    const int* src = ei;       // edge_index row 0
    const int* dst = ei + E;   // edge_index row 1

    char* ws = (char*)d_ws;
    size_t off = 0;
    auto alloc = [&](size_t bytes) -> void* {
        void* p = ws + off;
        off = (off + bytes + 511) & ~(size_t)511;
        return p;
    };
    float* bufA    = (float*)alloc((size_t)N * FDIM * 4);  // y (gemm out, *dinv)
    float* bufB    = (float*)alloc((size_t)N * FDIM * 4);  // h1
    int*   col     = (int*)alloc((size_t)E * 4);
    int*   deg     = (int*)alloc((size_t)N * 4);
    float* dinv    = (float*)alloc((size_t)N * 4);
    int*   row_ptr = (int*)alloc((size_t)(N + 1) * 4);
    int*   cursor  = (int*)alloc((size_t)(N + 1) * 4);
    int*   bsum    = (int*)alloc(256);
    int*   boff    = (int*)alloc(256);

    hipMemsetAsync(deg, 0, (size_t)N * 4, stream);
    k_deg<<<(E + 255) / 256, 256, 0, stream>>>(dst, deg, E);
    int nb = (N + 1023) / 1024;
    k_scan1<<<nb, 1024, 0, stream>>>(deg, row_ptr, bsum, N);
    k_scan2<<<1, 64, 0, stream>>>(bsum, boff, nb);
    k_scan3<<<(N + 1 + 255) / 256, 256, 0, stream>>>(row_ptr, cursor, boff, deg, dinv, N);
    k_fill<<<(E + 255) / 256, 256, 0, stream>>>(src, dst, cursor, col, E);

    // layer 1
    k_gemm<<<(N + 31) / 32, 256, 0, stream>>>(x, W1, dinv, bufA, N);
    k_agg<false><<<(N + 3) / 4, 256, 0, stream>>>(bufA, b1, dinv, row_ptr, col, bufB,
                                                  nullptr, nullptr, nullptr, N);
    // layer 2 + fused final projection
    k_gemm<<<(N + 31) / 32, 256, 0, stream>>>(bufB, W2, dinv, bufA, N);
    k_agg<true><<<(N + 3) / 4, 256, 0, stream>>>(bufA, b2, dinv, row_ptr, col, nullptr,
                                                 Wf, bf, (float*)d_out, N);
}

// Round 3
// 319.386 us; speedup vs baseline: 1.2412x; 1.2412x over previous
//
#include <hip/hip_runtime.h>
#include <hip/hip_bf16.h>

// GCN anomaly detector: 2x GCNConv(128->128, relu) + linear(128->1).
// CSR build -> [GEMM(fp32 acc)*dinv -> bf16 y -> gather-agg(+bias,relu)] x2,
// layer-2 agg fused with final Wf dot. Intermediates stored bf16 to halve the
// gather footprint (12.8 MB table vs 4 MB per-XCD L2); accumulation in fp32.

#define FDIM 128

typedef unsigned int uint;
typedef unsigned short ushort;

__device__ inline float2 bf2f(uint u) {
    // u = two packed bf16 (little endian): low ushort = element 0
    return make_float2(__uint_as_float(u << 16), __uint_as_float(u & 0xffff0000u));
}
__device__ inline ushort f2bf(float f) {
    uint u = __float_as_uint(f);
    return (ushort)((u + 0x7fffu + ((u >> 16) & 1u)) >> 16);  // RNE
}
__device__ inline uint packbf2(float a, float b) {
    return (uint)f2bf(a) | ((uint)f2bf(b) << 16);
}

// ---------------- CSR build ----------------

__global__ void k_deg(const int* __restrict__ dst, int* __restrict__ deg, int E) {
    int e = blockIdx.x * 256 + threadIdx.x;
    if (e < E) atomicAdd(&deg[dst[e]], 1);
}

__global__ void k_scan1(const int* __restrict__ deg, int* __restrict__ row_ptr,
                        int* __restrict__ blockSum, int n) {
    __shared__ int wsum[16];
    int i = blockIdx.x * 1024 + threadIdx.x;
    int lane = threadIdx.x & 63, wid = threadIdx.x >> 6;
    int v = (i < n) ? deg[i] : 0;
    int x = v;
    #pragma unroll
    for (int off = 1; off < 64; off <<= 1) {
        int y = __shfl_up(x, off);
        if (lane >= off) x += y;
    }
    if (lane == 63) wsum[wid] = x;
    __syncthreads();
    if (wid == 0) {
        int s = (lane < 16) ? wsum[lane] : 0;
        #pragma unroll
        for (int off = 1; off < 16; off <<= 1) {
            int y = __shfl_up(s, off);
            if (lane >= off) s += y;
        }
        if (lane < 16) wsum[lane] = s;
    }
    __syncthreads();
    int add = wid ? wsum[wid - 1] : 0;
    int incl = x + add;
    if (i < n) row_ptr[i + 1] = incl;
    if (threadIdx.x == 1023) blockSum[blockIdx.x] = incl;
}

__global__ void k_scan2(const int* __restrict__ blockSum, int* __restrict__ blockOff, int nb) {
    int lane = threadIdx.x;  // 64 threads; nb <= 64 (N <= 65536)
    int v = (lane < nb) ? blockSum[lane] : 0;
    int x = v;
    #pragma unroll
    for (int off = 1; off < 64; off <<= 1) {
        int y = __shfl_up(x, off);
        if (lane >= off) x += y;
    }
    blockOff[lane] = x - v;  // exclusive
}

__global__ void k_scan3(int* __restrict__ row_ptr, int* __restrict__ cursor,
                        const int* __restrict__ blockOff, const int* __restrict__ deg,
                        float* __restrict__ dinv, int n) {
    int i = blockIdx.x * 256 + threadIdx.x;
    if (i > n) return;
    if (i == 0) {
        row_ptr[0] = 0;
        cursor[0] = 0;
    } else {
        int b = (i - 1) >> 10;
        int val = row_ptr[i] + blockOff[b];
        row_ptr[i] = val;
        cursor[i] = val;
    }
    if (i < n) dinv[i] = rsqrtf((float)deg[i] + 1.0f);  // +1 self loop; always > 0
}

__global__ void k_fill(const int* __restrict__ src, const int* __restrict__ dst,
                       int* __restrict__ cursor, int* __restrict__ col, int E) {
    int e = blockIdx.x * 256 + threadIdx.x;
    if (e < E) {
        int pos = atomicAdd(&cursor[dst[e]], 1);
        col[pos] = src[e];
    }
}

// ---------------- GEMM: Y[r,:] = bf16( (X @ W)[r,:] * dinv[r] ) ----------------
// M x 128 @ 128 x 128, fp32 accumulate. Input fp32 (layer 1) or bf16 (layer 2).

#define FMA4(av, xs, wv) { (av).x += (xs) * (wv).x; (av).y += (xs) * (wv).y; \
                           (av).z += (xs) * (wv).z; (av).w += (xs) * (wv).w; }

template <bool BF16IN>
__global__ __launch_bounds__(256) void k_gemm(const void* __restrict__ Xv,
                                              const float* __restrict__ W,
                                              const float* __restrict__ dinv,
                                              uint* __restrict__ Y, int M) {
    __shared__ float4 Xs[32][16];  // [row][k4]  8 KB
    __shared__ float4 Ws[64][32];  // [k][col4] 32 KB
    const int t = threadIdx.x;
    const int tx = t & 31;   // col4 group: cols 4*tx..4*tx+3
    const int ty = t >> 5;   // row group:  rows 4*ty..4*ty+3
    const int rb = blockIdx.x * 32;

    float4 acc[4];
    #pragma unroll
    for (int i = 0; i < 4; ++i) acc[i] = make_float4(0.f, 0.f, 0.f, 0.f);

    for (int kc = 0; kc < 2; ++kc) {
        // stage X tile: 32 rows x 64 k
        #pragma unroll
        for (int it = 0; it < 2; ++it) {
            int idx = t + it * 256;
            int r = idx >> 4, j = idx & 15;
            int gr = rb + r;
            float4 v = make_float4(0.f, 0.f, 0.f, 0.f);
            if (gr < M) {
                if (BF16IN) {
                    const ushort* Xb = (const ushort*)Xv;
                    uint2 u = *(const uint2*)&Xb[(size_t)gr * FDIM + kc * 64 + 4 * j];
                    v.x = __uint_as_float(u.x << 16);
                    v.y = __uint_as_float(u.x & 0xffff0000u);
                    v.z = __uint_as_float(u.y << 16);
                    v.w = __uint_as_float(u.y & 0xffff0000u);
                } else {
                    const float* Xf = (const float*)Xv;
                    v = *(const float4*)&Xf[(size_t)gr * FDIM + kc * 64 + 4 * j];
                }
            }
            Xs[r][j] = v;
        }
        // stage W chunk: 64 k x 128 cols
        #pragma unroll
        for (int it = 0; it < 8; ++it) {
            int idx = t + it * 256;
            int kk = idx >> 5, c4 = idx & 31;
            Ws[kk][c4] = *(const float4*)&W[(size_t)(kc * 64 + kk) * FDIM + 4 * c4];
        }
        __syncthreads();
        #pragma unroll
        for (int k4 = 0; k4 < 16; ++k4) {
            float4 x0 = Xs[ty * 4 + 0][k4];
            float4 x1 = Xs[ty * 4 + 1][k4];
            float4 x2 = Xs[ty * 4 + 2][k4];
            float4 x3 = Xs[ty * 4 + 3][k4];
            float4 w0 = Ws[k4 * 4 + 0][tx];
            float4 w1 = Ws[k4 * 4 + 1][tx];
            float4 w2 = Ws[k4 * 4 + 2][tx];
            float4 w3 = Ws[k4 * 4 + 3][tx];
            FMA4(acc[0], x0.x, w0) FMA4(acc[0], x0.y, w1) FMA4(acc[0], x0.z, w2) FMA4(acc[0], x0.w, w3)
            FMA4(acc[1], x1.x, w0) FMA4(acc[1], x1.y, w1) FMA4(acc[1], x1.z, w2) FMA4(acc[1], x1.w, w3)
            FMA4(acc[2], x2.x, w0) FMA4(acc[2], x2.y, w1) FMA4(acc[2], x2.z, w2) FMA4(acc[2], x2.w, w3)
            FMA4(acc[3], x3.x, w0) FMA4(acc[3], x3.y, w1) FMA4(acc[3], x3.z, w2) FMA4(acc[3], x3.w, w3)
        }
        __syncthreads();
    }
    #pragma unroll
    for (int i = 0; i < 4; ++i) {
        int gr = rb + ty * 4 + i;
        if (gr < M) {
            float s = dinv[gr];
            float4 a = acc[i];
            uint2 o;
            o.x = packbf2(a.x * s, a.y * s);
            o.y = packbf2(a.z * s, a.w * s);
            *(uint2*)&Y[(size_t)gr * (FDIM / 2) + 2 * tx] = o;  // Y row = 64 uints (128 bf16)
        }
    }
}

// ------- Aggregation: h[d,:] = relu(dinv[d]*(y[d,:] + sum_{s in N(d)} y[s,:]) + b) -------
// y is bf16 (row = 256 B = 64 lanes x 1 dword). One wave per node; fp32 accumulate.
// Edge loop unrolled x4 for memory-level parallelism. FINAL fuses h . Wf + bf.

template <bool FINAL>
__global__ __launch_bounds__(256) void k_agg(const uint* __restrict__ y,
                                             const float* __restrict__ bvec,
                                             const float* __restrict__ dinv,
                                             const int* __restrict__ row_ptr,
                                             const int* __restrict__ col,
                                             uint* __restrict__ h,
                                             const float* __restrict__ Wf,
                                             const float* __restrict__ bf,
                                             float* __restrict__ out, int n) {
    int wid = threadIdx.x >> 6, lane = threadIdx.x & 63;
    int node = blockIdx.x * 4 + wid;
    if (node >= n) return;
    int beg = row_ptr[node], end = row_ptr[node + 1];
    float2 acc = bf2f(y[(size_t)node * 64 + lane]);  // self loop (y already *dinv[node])
    int e = beg;
    for (; e + 4 <= end; e += 4) {
        int s0 = col[e], s1 = col[e + 1], s2 = col[e + 2], s3 = col[e + 3];
        uint v0 = y[(size_t)s0 * 64 + lane];
        uint v1 = y[(size_t)s1 * 64 + lane];
        uint v2 = y[(size_t)s2 * 64 + lane];
        uint v3 = y[(size_t)s3 * 64 + lane];
        float2 f0 = bf2f(v0), f1 = bf2f(v1), f2 = bf2f(v2), f3 = bf2f(v3);
        acc.x += (f0.x + f1.x) + (f2.x + f3.x);
        acc.y += (f0.y + f1.y) + (f2.y + f3.y);
    }
    for (; e < end; ++e) {
        float2 f = bf2f(y[(size_t)col[e] * 64 + lane]);
        acc.x += f.x;
        acc.y += f.y;
    }
    float dn = dinv[node];
    float2 bb = *(const float2*)&bvec[lane * 2];
    float ox = fmaxf(fmaf(acc.x, dn, bb.x), 0.f);
    float oy = fmaxf(fmaf(acc.y, dn, bb.y), 0.f);
    if (FINAL) {
        float2 wf = *(const float2*)&Wf[lane * 2];
        float s = ox * wf.x + oy * wf.y;
        #pragma unroll
        for (int off = 32; off > 0; off >>= 1) s += __shfl_xor(s, off);
        if (lane == 0) out[node] = s + bf[0];
    } else {
        h[(size_t)node * 64 + lane] = packbf2(ox, oy);
    }
}

// ---------------- launch ----------------

extern "C" void kernel_launch(void* const* d_in, const int* in_sizes, int n_in,
                              void* d_out, int out_size, void* d_ws, size_t ws_size,
                              hipStream_t stream) {
    const float* x  = (const float*)d_in[0];
    const int*   ei = (const int*)d_in[1];
    const float* W1 = (const float*)d_in[2];
    const float* b1 = (const float*)d_in[3];
    const float* W2 = (const float*)d_in[4];
    const float* b2 = (const float*)d_in[5];
    const float* Wf = (const float*)d_in[6];
    const float* bf = (const float*)d_in[7];

    const int N = in_sizes[0] / FDIM;
    const int E = in_sizes[1] / 2;
    const int* src = ei;       // edge_index row 0
    const int* dst = ei + E;   // edge_index row 1

    char* ws = (char*)d_ws;
    size_t off = 0;
    auto alloc = [&](size_t bytes) -> void* {
        void* p = ws + off;
        off = (off + bytes + 511) & ~(size_t)511;
        return p;
    };
    uint*  bufA    = (uint*)alloc((size_t)N * FDIM * 2);  // y bf16 (gemm out, *dinv)
    uint*  bufB    = (uint*)alloc((size_t)N * FDIM * 2);  // h1 bf16
    int*   col     = (int*)alloc((size_t)E * 4);
    int*   deg     = (int*)alloc((size_t)N * 4);
    float* dinv    = (float*)alloc((size_t)N * 4);
    int*   row_ptr = (int*)alloc((size_t)(N + 1) * 4);
    int*   cursor  = (int*)alloc((size_t)(N + 1) * 4);
    int*   bsum    = (int*)alloc(256);
    int*   boff    = (int*)alloc(256);

    hipMemsetAsync(deg, 0, (size_t)N * 4, stream);
    k_deg<<<(E + 255) / 256, 256, 0, stream>>>(dst, deg, E);
    int nb = (N + 1023) / 1024;
    k_scan1<<<nb, 1024, 0, stream>>>(deg, row_ptr, bsum, N);
    k_scan2<<<1, 64, 0, stream>>>(bsum, boff, nb);
    k_scan3<<<(N + 1 + 255) / 256, 256, 0, stream>>>(row_ptr, cursor, boff, deg, dinv, N);
    k_fill<<<(E + 255) / 256, 256, 0, stream>>>(src, dst, cursor, col, E);

    // layer 1
    k_gemm<false><<<(N + 31) / 32, 256, 0, stream>>>(x, W1, dinv, bufA, N);
    k_agg<false><<<(N + 3) / 4, 256, 0, stream>>>(bufA, b1, dinv, row_ptr, col, bufB,
                                                  nullptr, nullptr, nullptr, N);
    // layer 2 + fused final projection
    k_gemm<true><<<(N + 31) / 32, 256, 0, stream>>>(bufB, W2, dinv, bufA, N);
    k_agg<true><<<(N + 3) / 4, 256, 0, stream>>>(bufA, b2, dinv, row_ptr, col, nullptr,
                                                 Wf, bf, (float*)d_out, N);
}